// Round 1
// baseline (536.199 us; speedup 1.0000x reference)
//
#include <hip/hip_runtime.h>
#include <math.h>

constexpr int HD    = 32;     // head dim
constexpr int LW    = 256;    // tokens per window (M * N_CAND)
constexpr int NWIN  = 128;    // number of windows (= B_)
constexpr int ROWS  = NWIN * LW;   // 32768 total rows
constexpr int QKVC  = 384;    // qkv columns
constexpr float SCALE = 0.17677669529663687f;  // 1/sqrt(32)

__device__ inline float dot4(const float4 a, const float4 b) {
  return a.x * b.x + a.y * b.y + a.z * b.z + a.w * b.w;
}

// ---------------- RPE gather: rpe_g[h][i4*64+j4][0:96] ----------------
// s in [0,32): scale*q_rpe   [32,64): k_rpe   [64,96): v_rpe
__global__ __launch_bounds__(256) void rpe_gather_kernel(
    const float* __restrict__ tab, const int* __restrict__ rel_idx,
    float* __restrict__ out)
{
  int gid = blockIdx.x * 256 + threadIdx.x;   // 4*4096*96 = 1,572,864 exact
  int s   = gid % 96;
  int hp  = gid / 96;
  int p   = hp & 4095;
  int h   = hp >> 12;
  float v = tab[(size_t)rel_idx[p] * 384 + h * 96 + s];
  if (s < 32) v *= SCALE;
  out[gid] = v;
}

// ---------------- C[M,N] = A[M,K] @ W[N,K]^T + bias ----------------
// grid (M/64, N/64), 256 threads, 4x4 micro-tile, cache-blocked (no LDS)
template <int N, int K>
__global__ __launch_bounds__(256) void gemm_nt_bias(
    const float* __restrict__ A, const float* __restrict__ W,
    const float* __restrict__ bias, float* __restrict__ C)
{
  const int tx = threadIdx.x & 15;
  const int ty = threadIdx.x >> 4;
  const int m0 = blockIdx.x * 64 + ty * 4;
  const int n0 = blockIdx.y * 64 + tx * 4;
  const float4* A0 = (const float4*)(A + (size_t)(m0 + 0) * K);
  const float4* A1 = (const float4*)(A + (size_t)(m0 + 1) * K);
  const float4* A2 = (const float4*)(A + (size_t)(m0 + 2) * K);
  const float4* A3 = (const float4*)(A + (size_t)(m0 + 3) * K);
  const float4* W0 = (const float4*)(W + (size_t)(n0 + 0) * K);
  const float4* W1 = (const float4*)(W + (size_t)(n0 + 1) * K);
  const float4* W2 = (const float4*)(W + (size_t)(n0 + 2) * K);
  const float4* W3 = (const float4*)(W + (size_t)(n0 + 3) * K);
  float acc[4][4] = {};
#pragma unroll 2
  for (int k4 = 0; k4 < K / 4; ++k4) {
    float4 a[4] = {A0[k4], A1[k4], A2[k4], A3[k4]};
    float4 b[4] = {W0[k4], W1[k4], W2[k4], W3[k4]};
#pragma unroll
    for (int im = 0; im < 4; ++im)
#pragma unroll
      for (int in = 0; in < 4; ++in)
        acc[im][in] += dot4(a[im], b[in]);
  }
  float4 bv = *(const float4*)(bias + n0);
  float bb[4] = {bv.x, bv.y, bv.z, bv.w};
#pragma unroll
  for (int im = 0; im < 4; ++im) {
    float4 r;
    r.x = acc[im][0] + bb[0];
    r.y = acc[im][1] + bb[1];
    r.z = acc[im][2] + bb[2];
    r.w = acc[im][3] + bb[3];
    *(float4*)(C + (size_t)(m0 + im) * N + n0) = r;
  }
}

// ---------------- fused window attention ----------------
// grid (NWIN, 4 heads), 256 threads: thread = one query row, online softmax.
// S_ij = (q*s)·K_j + (q*s)·k_rpe[i4,j4] + K_j·(s*q_rpe[i4,j4]) + mask[b,i,j]
//      = K_j·u + c0 + mask,  u = q*s + s*q_rpe,  c0 = (q*s)·k_rpe  (per j4)
// out_i = sum_j p_j V_j + sum_j4 pool_j4 * v_rpe[i4,j4]
__global__ __launch_bounds__(256) void attn_kernel(
    const float* __restrict__ qkv, const float* __restrict__ rpeg,
    const float* __restrict__ mask, float* __restrict__ out)
{
  __shared__ float kvs[2 * LW * HD];   // K then V, 64 KB
  const int b = blockIdx.x;
  const int h = blockIdx.y;
  const int tid = threadIdx.x;
  const size_t rowbase = (size_t)b * LW;

  // stage K (cols 128+h*32) and V (cols 256+h*32) into LDS
  for (int it = 0; it < 8; ++it) {
    int f = tid + 256 * it;            // 0..2047
    int j = f >> 3, d4 = f & 7;
    const float* src = qkv + (rowbase + j) * QKVC + h * HD + d4 * 4;
    *(float4*)(&kvs[j * HD + d4 * 4])            = *(const float4*)(src + 128);
    *(float4*)(&kvs[LW * HD + j * HD + d4 * 4])  = *(const float4*)(src + 256);
  }
  __syncthreads();

  const int i  = tid;
  const int i4 = i >> 2;
  float4 q[8];
  {
    const float4* qr = (const float4*)(qkv + (rowbase + i) * QKVC + h * HD);
#pragma unroll
    for (int d = 0; d < 8; ++d) {
      float4 t = qr[d];
      q[d] = make_float4(t.x * SCALE, t.y * SCALE, t.z * SCALE, t.w * SCALE);
    }
  }
  const float4* rp4base =
      (const float4*)(rpeg + ((size_t)h * 4096 + (size_t)i4 * 64) * 96);
  const float* mrow = mask + ((size_t)b * LW + i) * LW;

  float4 acc[8];
#pragma unroll
  for (int d = 0; d < 8; ++d) acc[d] = make_float4(0.f, 0.f, 0.f, 0.f);
  float m_run = -INFINITY, l_run = 0.f;

  for (int j4 = 0; j4 < 64; ++j4) {
    const float4* rp = rp4base + j4 * 24;   // 96 floats
    float4 u[8];
    float c0 = 0.f;
#pragma unroll
    for (int d = 0; d < 8; ++d) {
      float4 sq = rp[d];        // scale * q_rpe
      float4 kr = rp[8 + d];    // k_rpe
      u[d] = make_float4(q[d].x + sq.x, q[d].y + sq.y,
                         q[d].z + sq.z, q[d].w + sq.w);
      c0 += dot4(q[d], kr);
    }
    float4 mv = *(const float4*)(mrow + j4 * 4);
    float mvals[4] = {mv.x, mv.y, mv.z, mv.w};
    float pool = 0.f;
#pragma unroll
    for (int jc = 0; jc < 4; ++jc) {
      const int j = j4 * 4 + jc;
      const float4* kj = (const float4*)(&kvs[j * HD]);
      float s = c0 + mvals[jc];
#pragma unroll
      for (int d = 0; d < 8; ++d) s += dot4(u[d], kj[d]);
      if (s > m_run) {
        float r = __expf(m_run - s);
        m_run = s;
        l_run *= r; pool *= r;
#pragma unroll
        for (int d = 0; d < 8; ++d) {
          acc[d].x *= r; acc[d].y *= r; acc[d].z *= r; acc[d].w *= r;
        }
      }
      float p = __expf(s - m_run);
      l_run += p; pool += p;
      const float4* vj = (const float4*)(&kvs[LW * HD + j * HD]);
#pragma unroll
      for (int d = 0; d < 8; ++d) {
        acc[d].x += p * vj[d].x; acc[d].y += p * vj[d].y;
        acc[d].z += p * vj[d].z; acc[d].w += p * vj[d].w;
      }
    }
#pragma unroll
    for (int d = 0; d < 8; ++d) {
      float4 vr = rp[16 + d];
      acc[d].x += pool * vr.x; acc[d].y += pool * vr.y;
      acc[d].z += pool * vr.z; acc[d].w += pool * vr.w;
    }
  }
  float inv = 1.f / l_run;
  float4* orow = (float4*)(out + (rowbase + i) * (4 * HD) + h * HD);
#pragma unroll
  for (int d = 0; d < 8; ++d)
    orow[d] = make_float4(acc[d].x * inv, acc[d].y * inv,
                          acc[d].z * inv, acc[d].w * inv);
}

extern "C" void kernel_launch(void* const* d_in, const int* in_sizes, int n_in,
                              void* d_out, int out_size, void* d_ws, size_t ws_size,
                              hipStream_t stream) {
  (void)in_sizes; (void)n_in; (void)out_size; (void)ws_size;
  const float* x         = (const float*)d_in[0];
  const float* qkv_w     = (const float*)d_in[1];
  const float* qkv_b     = (const float*)d_in[2];
  const float* rpe_table = (const float*)d_in[3];
  const float* proj_w    = (const float*)d_in[4];
  const float* proj_b    = (const float*)d_in[5];
  const float* attn_mask = (const float*)d_in[6];
  const int*   rel_idx   = (const int*)d_in[7];
  float* out = (float*)d_out;

  float* qkvbuf = (float*)d_ws;                          // 32768*384 fp32 (50.3 MB)
  float* rpeg   = qkvbuf + (size_t)ROWS * QKVC;          // 4*4096*96  (6.3 MB)
  float* attnb  = rpeg + (size_t)4 * 4096 * 96;          // 32768*128  (16.8 MB)

  hipLaunchKernelGGL(rpe_gather_kernel, dim3(6144), dim3(256), 0, stream,
                     rpe_table, rel_idx, rpeg);
  hipLaunchKernelGGL((gemm_nt_bias<QKVC, 128>), dim3(ROWS / 64, QKVC / 64),
                     dim3(256), 0, stream, x, qkv_w, qkv_b, qkvbuf);
  hipLaunchKernelGGL(attn_kernel, dim3(NWIN, 4), dim3(256), 0, stream,
                     qkvbuf, rpeg, attn_mask, attnb);
  hipLaunchKernelGGL((gemm_nt_bias<128, 128>), dim3(ROWS / 64, 2),
                     dim3(256), 0, stream, attnb, proj_w, proj_b, out);
}